// Round 3
// baseline (673.148 us; speedup 1.0000x reference)
//
#include <hip/hip_runtime.h>
#include <hip/hip_bf16.h>
#include <stdint.h>

#define I_SIZE 256
#define D_DIM 128
#define BATCH 1024

typedef __attribute__((ext_vector_type(8))) short short8;
typedef __attribute__((ext_vector_type(4))) float floatx4;

__device__ inline float bf2f(short s) {
    union { uint32_t u; float f; } v; v.u = ((uint32_t)(uint16_t)s) << 16;
    return v.f;
}
__device__ inline uint32_t pkbf(float a, float b) {
    __hip_bfloat162 h = __float22bfloat162_rn(make_float2(a, b));
    union { __hip_bfloat162 h; uint32_t u; } v; v.h = h; return v.u;
}
__device__ inline float sigmoidf_fast(float x) { return 1.0f / (1.0f + __expf(-x)); }
__device__ inline float tanhf_fast(float x)    { return 2.0f / (1.0f + __expf(-2.0f * x)) - 1.0f; }

// LDS-only barrier: waits for LDS ops, does NOT drain vmcnt — global stores
// keep draining across the barrier.
#define BAR_LGKM() asm volatile("s_waitcnt lgkmcnt(0)\n\ts_barrier" ::: "memory")

// ============================================================================
// 256 blocks (1 group / CU), 1024 threads (16 waves, 4/SIMD).
// LDS (160 KiB exactly): Ut 96K (swizzled bf16 U^T r,z,h) + hgb 32K (hg) +
// pb 32K (p = r*hg). Swizzle: elem col of row at row*128 + ((col>>3)^(row&7))*8
// + (col&7)  — conflict-free b128 fragment reads (Ut-proven pattern).
//
// Wave (rg = w>>1, nh = w&1) owns rows r0=rg*16..+15.
// Per pass: r-GEMM FULL width (2x redundant across the nh pair, bit-identical)
// -> p for all 128 cols written to pb by BOTH waves (benign identical race)
// -> h-GEMM A-frags are self-produced: intra-wave lgkmcnt replaces barrier B.
// Only 2 workgroup barriers per pass (staging fence pair); waves desync so
// epilogue VALU overlaps other waves' MFMA/LDS phases.
// ============================================================================
__global__ __launch_bounds__(1024, 4) void gru_fused(
    const float* __restrict__ X, const float* __restrict__ H,
    const float* __restrict__ Wr, const float* __restrict__ Wz, const float* __restrict__ Wh,
    const float* __restrict__ Ur, const float* __restrict__ Uz, const float* __restrict__ Uh,
    const float* __restrict__ br, const float* __restrict__ bz, const float* __restrict__ bh,
    float* __restrict__ out)
{
    __shared__ short Ut[3 * D_DIM * D_DIM];   // 98304 B
    __shared__ short hgb[D_DIM * D_DIM];      // 32768 B (swizzled hg tile)
    __shared__ short pb [D_DIM * D_DIM];      // 32768 B (swizzled p tile)

    const int tid   = threadIdx.x;
    const int group = blockIdx.x;
    const int lane  = tid & 63;
    const int w     = tid >> 6;

    const int am = lane & 15;
    const int aq = lane >> 4;
    const int a7 = am & 7;
    const int ah = am >> 3;
    const int rg = w >> 1;
    const int nh = w & 1;
    const int r0 = rg * 16;
    const size_t HOFF = (size_t)BATCH * I_SIZE * D_DIM;

    // ---- W / bias in registers (full width for r; own half for z,h) ----
    float wrv[8], brv[8];
    #pragma unroll
    for (int t2 = 0; t2 < 8; ++t2) {
        wrv[t2] = Wr[group * D_DIM + t2 * 16 + am];
        brv[t2] = br[group * D_DIM + t2 * 16 + am];
    }
    float wzv[4], bzv[4], whv[4], bhv[4];
    #pragma unroll
    for (int t2 = 0; t2 < 4; ++t2) {
        const int c = nh * 64 + t2 * 16 + am;
        wzv[t2] = Wz[group * D_DIM + c]; bzv[t2] = bz[group * D_DIM + c];
        whv[t2] = Wh[group * D_DIM + c]; bhv[t2] = bh[group * D_DIM + c];
    }

    // ---- fused U transpose: fp32 coalesced rows -> swizzled bf16 LDS ----
    {
        const int kc = tid & 127;
        const int jb = tid >> 7;           // 0..7
        #pragma unroll
        for (int g = 0; g < 3; ++g) {
            const float* Ug = ((g == 0) ? Ur : (g == 1) ? Uz : Uh)
                              + (size_t)group * (D_DIM * D_DIM);
            short* dst = &Ut[g * (D_DIM * D_DIM)];
            #pragma unroll
            for (int m = 0; m < 4; ++m) {
                const int j0 = m * 8 + jb;                  // 0..31
                float a0 = Ug[(4 * j0 + 0) * D_DIM + kc];
                float a1 = Ug[(4 * j0 + 1) * D_DIM + kc];
                float a2 = Ug[(4 * j0 + 2) * D_DIM + kc];
                float a3 = Ug[(4 * j0 + 3) * D_DIM + kc];
                uint2 uu; uu.x = pkbf(a0, a1); uu.y = pkbf(a2, a3);
                const int p = (j0 >> 1) ^ (kc & 7);
                *(uint2*)&dst[kc * D_DIM + p * 8 + 4 * (j0 & 1)] = uu;
            }
        }
    }

    const int srow = tid >> 3;             // staging row 0..127
    const int sblk = (tid & 7) >> 1;       // col block base
    const int sof  = (tid & 7 & 1) * 4;    // col&7 ∈ {0,4}
    const int sr7  = (srow & 7) << 3;

    // ---- stage pass-0 hg ----
    #pragma unroll
    for (int it = 0; it < 4; ++it) {
        float4 v = *(const float4*)(H + (size_t)srow * (I_SIZE * D_DIM)
                                    + group * D_DIM + (tid & 7) * 4 + it * 32);
        uint2 uu; uu.x = pkbf(v.x, v.y); uu.y = pkbf(v.z, v.w);
        *(uint2*)&hgb[(srow << 7) + ((((sblk + it * 4) << 3) ^ sr7)) + sof] = uu;
    }
    BAR_LGKM();   // barrier A for pass 0

    int pswz[4];
    #pragma unroll
    for (int kk = 0; kk < 4; ++kk) pswz[kk] = (((4 * kk + aq) << 3) ^ (a7 << 3));

    const floatx4 zero = {0.f, 0.f, 0.f, 0.f};

    for (int pass = 0; pass < 8; ++pass) {
        const int R = pass * 128;

        // ---- A fragments (hg, own rows) ----
        short8 a[4];
        #pragma unroll
        for (int kk = 0; kk < 4; ++kk)
            a[kk] = *(const short8*)&hgb[((r0 + am) << 7) + pswz[kk]];

        // ---- X column values (quarter-group uniform address -> 4 req/wave) ----
        float Xv[4];
        #pragma unroll
        for (int pp = 0; pp < 4; ++pp)
            Xv[pp] = X[(size_t)(R + r0 + aq * 4 + pp) * I_SIZE + group];

        // ---- async prefetch of next-pass hg (hides under all 3 GEMMs) ----
        float4 pf[4];
        if (pass < 7) {
            #pragma unroll
            for (int it = 0; it < 4; ++it)
                pf[it] = *(const float4*)(H + (size_t)(R + 128 + srow) * (I_SIZE * D_DIM)
                                          + group * D_DIM + (tid & 7) * 4 + it * 32);
        }

        // ---- r GEMM: FULL width (8 n-tiles) ----
        floatx4 accr[8];
        #pragma unroll
        for (int t2 = 0; t2 < 8; ++t2) accr[t2] = zero;
        __builtin_amdgcn_s_setprio(1);
        #pragma unroll
        for (int t2 = 0; t2 < 8; ++t2) {
            const short* rowp = &Ut[(t2 * 16 + am) << 7];
            #pragma unroll
            for (int kk = 0; kk < 4; ++kk)
                accr[t2] = __builtin_amdgcn_mfma_f32_16x16x32_bf16(
                    a[kk], *(const short8*)(rowp + pswz[kk]), accr[t2], 0, 0, 0);
        }
        __builtin_amdgcn_s_setprio(0);

        // ---- epilogue 1: r gate full width; p = r*hg -> pb (swizzled) ----
        #pragma unroll
        for (int pp = 0; pp < 4; ++pp) {
            const int rl = r0 + aq * 4 + pp;
            const int rb = rl << 7;
            const int rx = (rl & 7) << 3;
            float pv[8];
            #pragma unroll
            for (int t2 = 0; t2 < 8; ++t2) {
                const float hgv = bf2f(hgb[rb + ((((t2 * 2 + ah) << 3) ^ rx)) + a7]);
                const float rv  = sigmoidf_fast(accr[t2][pp] + Xv[pp] * wrv[t2] + brv[t2]);
                pv[t2] = rv * hgv;
            }
            #pragma unroll
            for (int te = 0; te < 4; ++te) {
                const uint32_t u = pkbf(pv[2 * te], pv[2 * te + 1]);
                pb[rb + ((((4 * te + ah) << 3) ^ rx)) + a7]     = (short)(u & 0xFFFFu);
                pb[rb + ((((4 * te + 2 + ah) << 3) ^ rx)) + a7] = (short)(u >> 16);
            }
        }

        // ---- z GEMM: own half ----
        floatx4 accz[4];
        #pragma unroll
        for (int t2 = 0; t2 < 4; ++t2) accz[t2] = zero;
        __builtin_amdgcn_s_setprio(1);
        #pragma unroll
        for (int t2 = 0; t2 < 4; ++t2) {
            const short* rowp = &Ut[16384 + ((nh * 64 + t2 * 16 + am) << 7)];
            #pragma unroll
            for (int kk = 0; kk < 4; ++kk)
                accz[t2] = __builtin_amdgcn_mfma_f32_16x16x32_bf16(
                    a[kk], *(const short8*)(rowp + pswz[kk]), accz[t2], 0, 0, 0);
        }
        __builtin_amdgcn_s_setprio(0);

        // ---- intra-wave fence: own p writes retired before ap reads.
        //      (wave wrote ALL of its rowgroup's p; partner writes identical
        //      bits, so no workgroup barrier needed.) ----
        asm volatile("s_waitcnt lgkmcnt(0)" ::: "memory");
        __builtin_amdgcn_sched_barrier(0);

        // ---- h GEMM: A = p (self-produced), own half of N ----
        short8 ap[4];
        #pragma unroll
        for (int kk = 0; kk < 4; ++kk)
            ap[kk] = *(const short8*)&pb[((r0 + am) << 7) + pswz[kk]];

        floatx4 acch[4];
        #pragma unroll
        for (int t2 = 0; t2 < 4; ++t2) acch[t2] = zero;
        __builtin_amdgcn_s_setprio(1);
        #pragma unroll
        for (int t2 = 0; t2 < 4; ++t2) {
            const short* rowp = &Ut[32768 + ((nh * 64 + t2 * 16 + am) << 7)];
            #pragma unroll
            for (int kk = 0; kk < 4; ++kk)
                acch[t2] = __builtin_amdgcn_mfma_f32_16x16x32_bf16(
                    ap[kk], *(const short8*)(rowp + pswz[kk]), acch[t2], 0, 0, 0);
        }
        __builtin_amdgcn_s_setprio(0);

        // ---- epilogue 2: z, h_tilde, h_new, store (stores drain in bg) ----
        #pragma unroll
        for (int t2 = 0; t2 < 4; ++t2) {
            const int c  = nh * 64 + t2 * 16 + am;
            const int cb = (nh * 8 + t2 * 2 + ah) << 3;
            #pragma unroll
            for (int pp = 0; pp < 4; ++pp) {
                const int rl = r0 + aq * 4 + pp;
                const float hgv = bf2f(hgb[(rl << 7) + (cb ^ ((rl & 7) << 3)) + a7]);
                const float zv = sigmoidf_fast(accz[t2][pp] + Xv[pp] * wzv[t2] + bzv[t2]);
                const float ht = tanhf_fast(acch[t2][pp] + Xv[pp] * whv[t2] + bhv[t2]);
                const float hn = zv * hgv + (1.0f - zv) * ht;
                const size_t o = (size_t)(R + rl) * (I_SIZE * D_DIM) + group * D_DIM + c;
                out[o]        = hn;
                out[HOFF + o] = ht;
            }
        }

        if (pass < 7) {
            BAR_LGKM();   // barrier C: all waves done reading hgb
            #pragma unroll
            for (int it = 0; it < 4; ++it) {
                uint2 uu; uu.x = pkbf(pf[it].x, pf[it].y); uu.y = pkbf(pf[it].z, pf[it].w);
                *(uint2*)&hgb[(srow << 7) + ((((sblk + it * 4) << 3) ^ sr7)) + sof] = uu;
            }
            BAR_LGKM();   // barrier A for next pass
        }
    }
}

extern "C" void kernel_launch(void* const* d_in, const int* in_sizes, int n_in,
                              void* d_out, int out_size, void* d_ws, size_t ws_size,
                              hipStream_t stream) {
    const float* X  = (const float*)d_in[0];
    const float* H  = (const float*)d_in[1];
    const float* Wr = (const float*)d_in[2];
    const float* Wz = (const float*)d_in[3];
    const float* Wh = (const float*)d_in[4];
    const float* Ur = (const float*)d_in[5];
    const float* Uz = (const float*)d_in[6];
    const float* Uh = (const float*)d_in[7];
    const float* br = (const float*)d_in[8];
    const float* bz = (const float*)d_in[9];
    const float* bh = (const float*)d_in[10];

    (void)d_ws; (void)ws_size;   // workspace intentionally unused

    gru_fused<<<dim3(I_SIZE), dim3(1024), 0, stream>>>(
        X, H, Wr, Wz, Wh, Ur, Uz, Uh, br, bz, bh, (float*)d_out);
}